// Round 6
// baseline (199.444 us; speedup 1.0000x reference)
//
#include <hip/hip_runtime.h>
#include <stdint.h>

#define NB 8
#define NN 1024
#define LOG2E 1.44269504088896f

typedef short short8 __attribute__((ext_vector_type(8)));
typedef float floatx4 __attribute__((ext_vector_type(4)));

static __device__ __forceinline__ short f2bf(float x) {   // round-nearest-even
    union { float f; uint32_t u; } v; v.f = x;
    uint32_t r = (v.u + 0x7fffu + ((v.u >> 16) & 1u)) >> 16;
    return (short)r;
}

// ---------------- prep: adjacency bitmask + fp32->bf16 cvt + gsum zero ------
__global__ __launch_bounds__(256) void prep_all(const int* __restrict__ adj,
        uint64_t* __restrict__ am,
        const float* __restrict__ x0, const float* __restrict__ w1,
        const float* __restrict__ w2, const float* __restrict__ w3,
        const float* __restrict__ wn,
        ushort* __restrict__ x0b, ushort* __restrict__ wb1,
        ushort* __restrict__ wb2, ushort* __restrict__ wb3,
        ushort* __restrict__ wnb, float* __restrict__ gsum) {
    if (blockIdx.x < 2048) {
        int wave = blockIdx.x * 4 + (threadIdx.x >> 6);
        int lane = threadIdx.x & 63;
        int b = wave >> 10;
        int i = wave & 1023;
        const int* row = adj + ((size_t)b * NN + i) * NN;
        uint64_t* outp = am + ((size_t)b * NN + i) * 16;
        for (int it = 0; it < 16; ++it) {
            int j = it * 64 + lane;
            int v = (row[j] > 0) || (j == i);
            uint64_t m = __ballot(v);
            if (lane == 0) outp[it] = m;
        }
        return;
    }
    int idx = (blockIdx.x - 2048) * 256 + threadIdx.x;
    const float* src; ushort* dst; int li;
    if (idx < 131072)      { src = x0; dst = x0b; li = idx; }
    else if (idx < 135168) { src = w1; dst = wb1; li = idx - 131072; }
    else if (idx < 151552) { src = w2; dst = wb2; li = idx - 135168; }
    else if (idx < 155648) { src = w3; dst = wb3; li = idx - 151552; }
    else if (idx < 156672) { src = wn; dst = wnb; li = idx - 155648; }
    else if (idx < 156800) {
        ((float4*)gsum)[idx - 156672] = make_float4(0.f, 0.f, 0.f, 0.f);
        return;
    } else return;
    float4 v = ((const float4*)src)[li];
    ushort4 o;
    o.x = (ushort)f2bf(v.x); o.y = (ushort)f2bf(v.y);
    o.z = (ushort)f2bf(v.z); o.w = (ushort)f2bf(v.w);
    ((ushort4*)dst)[li] = o;
}

// ---------------- MFMA GEMM: H = X @ W^T, fused s/d epilogue, LDS-transposed
template<int K>
__global__ __launch_bounds__(256, 4) void gemm_mfma(const ushort* __restrict__ X,
        const ushort* __restrict__ Wt, ushort* __restrict__ hbT,
        const float* __restrict__ asrc, const float* __restrict__ adst,
        float* __restrict__ s_t, float* __restrict__ d_t, int nheads) {
    __shared__ ushort smem[2][64][88];
    int m0 = blockIdx.x * 64, n0 = blockIdx.y * 64;
    int hd = blockIdx.y;
    int tid = threadIdx.x, w = tid >> 6, L = tid & 63;
    int m15 = L & 15, kq = L >> 4;
    floatx4 acc[4];
#pragma unroll
    for (int ct = 0; ct < 4; ++ct) acc[ct] = (floatx4){0.f, 0.f, 0.f, 0.f};

    for (int k0 = 0; k0 < K; k0 += 64) {
#pragma unroll
        for (int it = 0; it < 2; ++it) {
            int idx = tid + it * 256;
            int r = idx >> 3, sg = idx & 7;
            *(uint4*)&smem[0][r][sg * 8] = *(const uint4*)&X[(size_t)(m0 + r) * K + k0 + sg * 8];
            *(uint4*)&smem[1][r][sg * 8] = *(const uint4*)&Wt[(size_t)(n0 + r) * K + k0 + sg * 8];
        }
        __syncthreads();
#pragma unroll
        for (int ks = 0; ks < 2; ++ks) {
            short8 a = *(const short8*)&smem[0][16 * w + m15][ks * 32 + kq * 8];
#pragma unroll
            for (int ct = 0; ct < 4; ++ct) {
                short8 bfr = *(const short8*)&smem[1][ct * 16 + m15][ks * 32 + kq * 8];
                acc[ct] = __builtin_amdgcn_mfma_f32_16x16x32_bf16(a, bfr, acc[ct], 0, 0, 0);
            }
        }
        __syncthreads();
    }

    float asv[4], adv[4];
#pragma unroll
    for (int ct = 0; ct < 4; ++ct) {
        asv[ct] = asrc[hd * 64 + ct * 16 + m15];
        adv[ct] = adst[hd * 64 + ct * 16 + m15];
    }
#pragma unroll
    for (int r = 0; r < 4; ++r) {
        float sp = acc[0][r] * asv[0] + acc[1][r] * asv[1] + acc[2][r] * asv[2] + acc[3][r] * asv[3];
        float dp = acc[0][r] * adv[0] + acc[1][r] * adv[1] + acc[2][r] * adv[2] + acc[3][r] * adv[3];
#pragma unroll
        for (int off = 1; off < 16; off <<= 1) {
            sp += __shfl_xor(sp, off);
            dp += __shfl_xor(dp, off);
        }
        if (m15 == 0) {
            int mg = m0 + 16 * w + kq * 4 + r;
            int bb = mg >> 10, node = mg & 1023;
            s_t[((size_t)(bb * nheads + hd)) * NN + node] = sp;
            d_t[((size_t)(bb * nheads + hd)) * NN + node] = dp;
        }
    }

    ushort* tb = (ushort*)smem;          // stride 80
#pragma unroll
    for (int ct = 0; ct < 4; ++ct)
#pragma unroll
        for (int r = 0; r < 4; ++r)
            tb[(ct * 16 + m15) * 80 + 16 * w + kq * 4 + r] = (ushort)f2bf(acc[ct][r]);
    __syncthreads();
    int bb = m0 >> 10, node0 = m0 & 1023;
    size_t base = ((size_t)(bb * nheads + hd) * 64) * NN + node0;
    int c = tid >> 2, s2 = (tid & 3) * 2;
#pragma unroll
    for (int e = 0; e < 2; ++e) {
        int sg = s2 + e;
        *(uint4*)&hbT[base + (size_t)c * NN + sg * 8] = *(const uint4*)&tb[c * 80 + sg * 8];
    }
}

// ---------------- MFMA masked-softmax aggregation, direct-global B ----------
// ROWS=32 (H=4 layers): grid (32,nheads,8)=1024 blocks; each wave owns a
// j-quarter and 2 row-groups sharing each B-fragment. ROWS=16 (layer 3):
// grid (64,1,8)=512. B-frags load straight from the L2-resident hbT slice —
// no LDS staging, no ds hazards, zero barriers in the j-loop.
template<int ROWS>
__global__ __launch_bounds__(256, 4) void gat_agg_mfma(
        const ushort* __restrict__ hbT, const uint64_t* __restrict__ am,
        const float* __restrict__ s_t, const float* __restrict__ d_t,
        const float* __restrict__ bias, ushort* __restrict__ Xb,
        float* __restrict__ gsum, int nheads, int do_colsum) {
    constexpr int RG = ROWS / 16;
    __shared__ __align__(16) float s_lds[NN];            // 4 KB
    __shared__ float red4[4];
    __shared__ float lden[4][RG][16];
    __shared__ __align__(16) float fb[4][ROWS][68];      // partial-acc overlay

    int i0 = blockIdx.x * ROWS;
    int hd = blockIdx.y;
    int b  = blockIdx.z;
    int HC = nheads * 64;
    int tid = threadIdx.x, w = tid >> 6, L = tid & 63;
    int m15 = L & 15, kq = L >> 4;

    // stage s + global max
    const float* srow = s_t + ((size_t)b * nheads + hd) * NN;
    float4 s4 = ((const float4*)srow)[tid];
    *(float4*)&s_lds[tid * 4] = s4;
    float lm = fmaxf(fmaxf(s4.x, s4.y), fmaxf(s4.z, s4.w));
#pragma unroll
    for (int off = 32; off; off >>= 1) lm = fmaxf(lm, __shfl_xor(lm, off));
    if (L == 0) red4[w] = lm;

    // per-lane adjacency words + d_i for each row-group
    uint64_t aw[RG][4];
    float d_i[RG];
#pragma unroll
    for (int rg = 0; rg < RG; ++rg) {
        const uint64_t* amrow = am + ((size_t)b * NN + i0 + rg * 16 + m15) * 16 + w * 4;
        *(uint4*)&aw[rg][0] = *(const uint4*)&amrow[0];
        *(uint4*)&aw[rg][2] = *(const uint4*)&amrow[2];
        d_i[rg] = d_t[((size_t)b * nheads + hd) * NN + i0 + rg * 16 + m15];
    }
    __syncthreads();

    float smax = fmaxf(fmaxf(red4[0], red4[1]), fmaxf(red4[2], red4[3]));
    float m2n[RG];
#pragma unroll
    for (int rg = 0; rg < RG; ++rg) {
        float t0 = smax + d_i[rg];
        float m_up = fmaxf(t0, 0.2f * t0);   // exp-safe upper bound
        m2n[rg] = -m_up * LOG2E;
    }

    floatx4 acc[4][RG];
#pragma unroll
    for (int ct = 0; ct < 4; ++ct)
#pragma unroll
        for (int rg = 0; rg < RG; ++rg) acc[ct][rg] = (floatx4){0.f, 0.f, 0.f, 0.f};
    float lsum[RG];
#pragma unroll
    for (int rg = 0; rg < RG; ++rg) lsum[rg] = 0.f;

    const ushort* hb = hbT + ((size_t)(b * nheads + hd) * 64) * NN;

#pragma unroll
    for (int t = 0; t < 4; ++t) {
        int jc = w * 4 + t;
#pragma unroll
        for (int ks = 0; ks < 2; ++ks) {
            int jb = jc * 64 + ks * 32 + kq * 8;
            // B-frags straight from global (L2-hot)
            short8 bfr[4];
#pragma unroll
            for (int ct = 0; ct < 4; ++ct)
                *(uint4*)&bfr[ct] = *(const uint4*)&hb[(size_t)(ct * 16 + m15) * NN + jb];
            float sv[8];
            *(float4*)&sv[0] = *(const float4*)&s_lds[jb];
            *(float4*)&sv[4] = *(const float4*)&s_lds[jb + 4];
#pragma unroll
            for (int rg = 0; rg < RG; ++rg) {
                unsigned byte = (unsigned)((aw[rg][t] >> (ks * 32 + kq * 8)) & 0xffull);
                unsigned ue[8];
#pragma unroll
                for (int u = 0; u < 8; ++u) {
                    float sc = sv[u] + d_i[rg];
                    float lk = fmaxf(sc, 0.2f * sc);
#if __has_builtin(__builtin_amdgcn_exp2f)
                    float arg = __builtin_fmaf(lk, LOG2E, m2n[rg]);
                    arg = ((byte >> u) & 1u) ? arg : -1e30f;
                    float e = __builtin_amdgcn_exp2f(arg);
#else
                    float e = __expf(fminf(lk + m2n[rg], 0.f));
                    e = ((byte >> u) & 1u) ? e : 0.f;
#endif
                    lsum[rg] += e;
                    ue[u] = __float_as_uint(e);
                }
                unsigned pk[4];
#pragma unroll
                for (int k2 = 0; k2 < 4; ++k2)
#if __has_builtin(__builtin_amdgcn_perm)
                    pk[k2] = __builtin_amdgcn_perm(ue[2 * k2 + 1], ue[2 * k2], 0x07060302u);
#else
                    pk[k2] = (ue[2 * k2] >> 16) | (ue[2 * k2 + 1] & 0xffff0000u);
#endif
                short8 afrag;
                *(uint4*)&afrag = *(uint4*)&pk[0];
#pragma unroll
                for (int ct = 0; ct < 4; ++ct)
                    acc[ct][rg] = __builtin_amdgcn_mfma_f32_16x16x32_bf16(afrag, bfr[ct], acc[ct][rg], 0, 0, 0);
            }
        }
    }

    // partial denoms (sum over kq groups) + publish partials
#pragma unroll
    for (int rg = 0; rg < RG; ++rg) {
        lsum[rg] += __shfl_xor(lsum[rg], 16);
        lsum[rg] += __shfl_xor(lsum[rg], 32);
        if (kq == 0) lden[w][rg][m15] = lsum[rg];
#pragma unroll
        for (int ct = 0; ct < 4; ++ct)
#pragma unroll
            for (int r = 0; r < 4; ++r)
                fb[w][rg * 16 + kq * 4 + r][ct * 16 + m15] = acc[ct][rg][r];
    }
    __syncthreads();

    // combine 4 waves' partials; epilogue relu(acc/l + bias) -> bf16
    if (ROWS == 32) {
        int rr = tid >> 3, c0 = (tid & 7) * 8;
        float s0[8];
#pragma unroll
        for (int k2 = 0; k2 < 8; ++k2) s0[k2] = 0.f;
        float ltot = 0.f;
#pragma unroll
        for (int w2 = 0; w2 < 4; ++w2) {
            float4 a4 = *(const float4*)&fb[w2][rr][c0];
            float4 b4 = *(const float4*)&fb[w2][rr][c0 + 4];
            s0[0] += a4.x; s0[1] += a4.y; s0[2] += a4.z; s0[3] += a4.w;
            s0[4] += b4.x; s0[5] += b4.y; s0[6] += b4.z; s0[7] += b4.w;
            ltot += lden[w2][rr >> 4][rr & 15];
        }
        float li = 1.f / ltot;
        float4 bv0 = *(const float4*)&bias[hd * 64 + c0];
        float4 bv1 = *(const float4*)&bias[hd * 64 + c0 + 4];
        float bvv[8] = {bv0.x, bv0.y, bv0.z, bv0.w, bv1.x, bv1.y, bv1.z, bv1.w};
        ushort o[8];
#pragma unroll
        for (int k2 = 0; k2 < 8; ++k2) {
            float v = fmaxf(s0[k2] * li + bvv[k2], 0.f);
            o[k2] = (ushort)f2bf(v);
        }
        *(uint4*)&Xb[((size_t)(b * NN + i0 + rr)) * HC + hd * 64 + c0] = *(uint4*)&o[0];
    } else {
        int rr = tid >> 4, c0 = (tid & 15) * 4;
        float s0 = 0.f, s1 = 0.f, s2 = 0.f, s3 = 0.f, ltot = 0.f;
#pragma unroll
        for (int w2 = 0; w2 < 4; ++w2) {
            float4 a4 = *(const float4*)&fb[w2][rr][c0];
            s0 += a4.x; s1 += a4.y; s2 += a4.z; s3 += a4.w;
            ltot += lden[w2][0][rr];
        }
        float li = 1.f / ltot;
        float4 bv = *(const float4*)&bias[hd * 64 + c0];
        float v0 = fmaxf(s0 * li + bv.x, 0.f);
        float v1 = fmaxf(s1 * li + bv.y, 0.f);
        float v2 = fmaxf(s2 * li + bv.z, 0.f);
        float v3 = fmaxf(s3 * li + bv.w, 0.f);
        ushort4 o;
        o.x = (ushort)f2bf(v0); o.y = (ushort)f2bf(v1);
        o.z = (ushort)f2bf(v2); o.w = (ushort)f2bf(v3);
        *(ushort4*)&Xb[((size_t)(b * NN + i0 + rr)) * HC + hd * 64 + c0] = o;
        if (do_colsum) {
            __syncthreads();
            *(float4*)&fb[0][rr][c0] = make_float4(v0, v1, v2, v3);
            __syncthreads();
            if (tid < 64) {
                float s = 0.f;
#pragma unroll
                for (int r2 = 0; r2 < 16; ++r2) s += fb[0][r2][tid];
                atomicAdd(&gsum[b * 64 + tid], s);
            }
        }
    }
}

// ---------------- fused readout: gc + relu(X@wn.T+bn)·wv + gc ----------------
__global__ __launch_bounds__(256) void readout_fused(
        const ushort* __restrict__ xb, const ushort* __restrict__ wnb,
        const float* __restrict__ bn, const float* __restrict__ wg,
        const float* __restrict__ bg, const float* __restrict__ wv,
        const float* __restrict__ bv, const float* __restrict__ gsum,
        float* __restrict__ outp) {
    __shared__ ushort xs[64][88];
    __shared__ ushort wns[64][88];
    __shared__ float gcs;
    int b = blockIdx.y, n0 = blockIdx.x * 64;
    int tid = threadIdx.x, w = tid >> 6, L = tid & 63;
    int m15 = L & 15, kq = L >> 4;
#pragma unroll
    for (int it = 0; it < 2; ++it) {
        int idx = tid + it * 256;
        int r = idx >> 3, sg = idx & 7;
        *(uint4*)&xs[r][sg * 8]  = *(const uint4*)&xb[(size_t)(b * NN + n0 + r) * 64 + sg * 8];
        *(uint4*)&wns[r][sg * 8] = *(const uint4*)&wnb[r * 64 + sg * 8];
    }
    if (tid < 64) {
        float acc = bg[tid];
#pragma unroll 8
        for (int c = 0; c < 64; ++c) acc += gsum[b * 64 + c] * wg[tid * 64 + c];
        acc = fmaxf(acc, 0.f) * wv[64 + tid];
#pragma unroll
        for (int off = 32; off; off >>= 1) acc += __shfl_down(acc, off);
        if (tid == 0) gcs = acc + bv[0];
    }
    __syncthreads();

    floatx4 acc[4];
#pragma unroll
    for (int ct = 0; ct < 4; ++ct) acc[ct] = (floatx4){0.f, 0.f, 0.f, 0.f};
#pragma unroll
    for (int ks = 0; ks < 2; ++ks) {
        short8 a = *(const short8*)&xs[16 * w + m15][ks * 32 + kq * 8];
#pragma unroll
        for (int ct = 0; ct < 4; ++ct) {
            short8 bfr = *(const short8*)&wns[ct * 16 + m15][ks * 32 + kq * 8];
            acc[ct] = __builtin_amdgcn_mfma_f32_16x16x32_bf16(a, bfr, acc[ct], 0, 0, 0);
        }
    }
    float bnv[4], wvv[4];
#pragma unroll
    for (int ct = 0; ct < 4; ++ct) {
        bnv[ct] = bn[ct * 16 + m15];
        wvv[ct] = wv[ct * 16 + m15];
    }
    float gc = gcs;
#pragma unroll
    for (int r = 0; r < 4; ++r) {
        float rp = 0.f;
#pragma unroll
        for (int ct = 0; ct < 4; ++ct)
            rp += fmaxf(acc[ct][r] + bnv[ct], 0.f) * wvv[ct];
#pragma unroll
        for (int off = 1; off < 16; off <<= 1) rp += __shfl_xor(rp, off);
        if (m15 == 0)
            outp[(size_t)b * NN + n0 + 16 * w + kq * 4 + r] = rp + gc;
    }
}

extern "C" void kernel_launch(void* const* d_in, const int* in_sizes, int n_in,
                              void* d_out, int out_size, void* d_ws, size_t ws_size,
                              hipStream_t stream) {
    const float* x0  = (const float*)d_in[0];
    const int*   adj = (const int*)  d_in[1];
    const float* w1  = (const float*)d_in[2];
    const float* as1 = (const float*)d_in[3];
    const float* ad1 = (const float*)d_in[4];
    const float* b1  = (const float*)d_in[5];
    const float* w2  = (const float*)d_in[6];
    const float* as2 = (const float*)d_in[7];
    const float* ad2 = (const float*)d_in[8];
    const float* b2  = (const float*)d_in[9];
    const float* w3  = (const float*)d_in[10];
    const float* as3 = (const float*)d_in[11];
    const float* ad3 = (const float*)d_in[12];
    const float* b3  = (const float*)d_in[13];
    const float* wn  = (const float*)d_in[14];
    const float* bn  = (const float*)d_in[15];
    const float* wg  = (const float*)d_in[16];
    const float* bg  = (const float*)d_in[17];
    const float* wv  = (const float*)d_in[18];
    const float* bv  = (const float*)d_in[19];
    float* outp = (float*)d_out;

    char* wsb = (char*)d_ws;
    uint64_t* amask = (uint64_t*)(wsb);                      // 1 MB
    ushort* hbT  = (ushort*)(wsb + (1u  << 20));             // 4 MB
    ushort* xbA  = (ushort*)(wsb + (5u  << 20));             // 4 MB
    ushort* xbB  = (ushort*)(wsb + (9u  << 20));             // 4 MB
    ushort* x0b  = (ushort*)(wsb + (13u << 20));             // 1 MB
    char* tail   = wsb + (14u << 20);
    float* s_buf = (float*)(tail);                           // 128 KB
    float* d_buf = (float*)(tail + (1u << 17));              // 128 KB
    ushort* wb1  = (ushort*)(tail + (2u << 17));             // 32 KB
    ushort* wb2  = (ushort*)(tail + (2u << 17) + (1u << 15));// 128 KB
    ushort* wb3  = (ushort*)(tail + (2u << 17) + (5u << 15));// 32 KB
    ushort* wnb  = (ushort*)(tail + (2u << 17) + (6u << 15));// 8 KB
    float* gsum  = (float*) (tail + (2u << 17) + (6u << 15) + (1u << 13));

    prep_all<<<2661, 256, 0, stream>>>(adj, amask, x0, w1, w2, w3, wn,
                                       x0b, wb1, wb2, wb3, wnb, gsum);

    // layer 1 (K=64, H=4)
    gemm_mfma<64><<<dim3(128, 4), 256, 0, stream>>>(x0b, wb1, hbT, as1, ad1, s_buf, d_buf, 4);
    gat_agg_mfma<32><<<dim3(32, 4, 8), 256, 0, stream>>>(hbT, amask, s_buf, d_buf, b1, xbA, gsum, 4, 0);

    // layer 2 (K=256, H=4)
    gemm_mfma<256><<<dim3(128, 4), 256, 0, stream>>>(xbA, wb2, hbT, as2, ad2, s_buf, d_buf, 4);
    gat_agg_mfma<32><<<dim3(32, 4, 8), 256, 0, stream>>>(hbT, amask, s_buf, d_buf, b2, xbB, gsum, 4, 0);

    // layer 3 (K=256, H=1) + fused column-sum
    gemm_mfma<256><<<dim3(128, 1), 256, 0, stream>>>(xbB, wb3, hbT, as3, ad3, s_buf, d_buf, 1);
    gat_agg_mfma<16><<<dim3(64, 1, 8), 256, 0, stream>>>(hbT, amask, s_buf, d_buf, b3, xbA, gsum, 1, 1);

    // fused readout
    readout_fused<<<dim3(16, 8), 256, 0, stream>>>(xbA, wnb, bn, wg, bg, wv, bv, gsum, outp);
}